// Round 1
// baseline (148.901 us; speedup 1.0000x reference)
//
#include <hip/hip_runtime.h>

// GNNDecoder: x_hat = GE[batch] @ node_w.T + node_b ; edge_hat = GE[batch[src]] @ edge_w.T + edge_b
// Restructured: per-graph projections P=[B,FN], Q=[B,FE] computed once (tiny GEMM),
// then outputs are pure row-gathers (memory-bound, ~512MB writes).

#define H   256
#define FN  128
#define FE  64
#define GPB 8    // graphs per proj block

__global__ __launch_bounds__(192) void proj_kernel(
    const float* __restrict__ ge,      // [B, H]
    const float* __restrict__ node_w,  // [FN, H]
    const float* __restrict__ node_b,  // [FN]
    const float* __restrict__ edge_w,  // [FE, H]
    const float* __restrict__ edge_b,  // [FE]
    float* __restrict__ P,             // [B, FN]
    float* __restrict__ Q)             // [B, FE]
{
    __shared__ float sge[GPB * H];
    const int t  = threadIdx.x;            // 0..191; waves 0,1 = node cols, wave 2 = edge cols
    const int g0 = blockIdx.x * GPB;

    // Stage 8 GE rows (8 KB) into LDS, float4-vectorized, coalesced.
    const float4* ge4  = reinterpret_cast<const float4*>(ge + (size_t)g0 * H);
    float4*       sge4 = reinterpret_cast<float4*>(sge);
    for (int i = t; i < GPB * H / 4; i += 192) sge4[i] = ge4[i];
    __syncthreads();

    const float4* w4;
    float bias;
    if (t < FN) { w4 = reinterpret_cast<const float4*>(node_w + (size_t)t * H);      bias = node_b[t]; }
    else        { w4 = reinterpret_cast<const float4*>(edge_w + (size_t)(t-FN) * H); bias = edge_b[t-FN]; }

    float acc[GPB];
    #pragma unroll
    for (int g = 0; g < GPB; ++g) acc[g] = 0.f;

    #pragma unroll 4
    for (int k = 0; k < H / 4; ++k) {
        const float4 wv = w4[k];
        #pragma unroll
        for (int g = 0; g < GPB; ++g) {
            const float* s = sge + g * H + k * 4;   // same addr across lanes -> LDS broadcast
            acc[g] += wv.x * s[0] + wv.y * s[1] + wv.z * s[2] + wv.w * s[3];
        }
    }

    #pragma unroll
    for (int g = 0; g < GPB; ++g) {
        const float v = acc[g] + bias;
        if (t < FN) P[(size_t)(g0 + g) * FN + t]        = v;
        else        Q[(size_t)(g0 + g) * FE + (t - FN)] = v;
    }
}

// x_hat[i,:] = P[batch[i],:]   — i over N rows, 32 float4 per row
__global__ __launch_bounds__(256) void node_scatter(
    const int* __restrict__ batch,
    const float4* __restrict__ P4,     // [B*32]
    float4* __restrict__ out4,         // [N*32]
    int total4, int Bm1)
{
    const int stride = gridDim.x * blockDim.x;
    for (int i = blockIdx.x * blockDim.x + threadIdx.x; i < total4; i += stride) {
        const int row = i >> 5;
        const int c   = i & 31;
        int g = batch[row];
        g = g & Bm1;                              // safety clamp (B is pow2)
        out4[i] = P4[((size_t)g << 5) + c];
    }
}

// edge_hat[e,:] = Q[batch[src[e]],:] — e over E rows, 16 float4 per row
__global__ __launch_bounds__(256) void edge_scatter(
    const int* __restrict__ batch,
    const int* __restrict__ src,       // edge_index row 0 (first E elements)
    const float4* __restrict__ Q4,     // [B*16]
    float4* __restrict__ out4,         // [E*16]
    int total4, int Bm1, int Nm1)
{
    const int stride = gridDim.x * blockDim.x;
    for (int i = blockIdx.x * blockDim.x + threadIdx.x; i < total4; i += stride) {
        const int e = i >> 4;
        const int c = i & 15;
        int s = src[e];
        s = min(max(s, 0), Nm1);                  // safety clamp
        int g = batch[s];
        g = g & Bm1;
        out4[i] = Q4[((size_t)g << 4) + c];
    }
}

extern "C" void kernel_launch(void* const* d_in, const int* in_sizes, int n_in,
                              void* d_out, int out_size, void* d_ws, size_t ws_size,
                              hipStream_t stream) {
    const float* ge     = (const float*)d_in[0];
    const int*   batch  = (const int*)  d_in[1];
    const int*   eidx   = (const int*)  d_in[2];
    const float* node_w = (const float*)d_in[3];
    const float* node_b = (const float*)d_in[4];
    const float* edge_w = (const float*)d_in[5];
    const float* edge_b = (const float*)d_in[6];

    const int B = in_sizes[0] / H;   // 4096
    const int N = in_sizes[1];       // 500000
    const int E = in_sizes[2] / 2;   // 1000000

    float* P = (float*)d_ws;                 // [B, FN]
    float* Q = P + (size_t)B * FN;           // [B, FE]

    float* x_hat = (float*)d_out;            // [N, FN]
    float* e_hat = x_hat + (size_t)N * FN;   // [E, FE]

    proj_kernel<<<B / GPB, 192, 0, stream>>>(ge, node_w, node_b, edge_w, edge_b, P, Q);

    const int total_n4 = N * (FN / 4);       // 16,000,000
    node_scatter<<<2048, 256, 0, stream>>>(batch, (const float4*)P, (float4*)x_hat,
                                           total_n4, B - 1);

    const int total_e4 = E * (FE / 4);       // 16,000,000
    edge_scatter<<<2048, 256, 0, stream>>>(batch, eidx, (const float4*)Q, (float4*)e_hat,
                                           total_e4, B - 1, N - 1);
}

// Round 2
// 110.861 us; speedup vs baseline: 1.3431x; 1.3431x over previous
//
#include <hip/hip_runtime.h>

// GNNDecoder: x_hat = GE[batch] @ node_w.T + node_b ; edge_hat = GE[batch[src]] @ edge_w.T + edge_b
// Restructured: per-graph projections P=[B,FN], Q=[B,FE] computed once (tiny GEMM),
// then outputs are pure row-gathers (memory-bound, 512MB writes).
// R2: fused scatters + NON-TEMPORAL stores so the 512MB write stream doesn't
// evict the hot gather tables (P/Q/batch) from per-XCD L2.

#define H   256
#define FN  128
#define FE  64
#define GPB 8    // graphs per proj block

typedef float f4 __attribute__((ext_vector_type(4)));

__global__ __launch_bounds__(192) void proj_kernel(
    const float* __restrict__ ge,      // [B, H]
    const float* __restrict__ node_w,  // [FN, H]
    const float* __restrict__ node_b,  // [FN]
    const float* __restrict__ edge_w,  // [FE, H]
    const float* __restrict__ edge_b,  // [FE]
    float* __restrict__ P,             // [B, FN]
    float* __restrict__ Q)             // [B, FE]
{
    __shared__ float sge[GPB * H];
    const int t  = threadIdx.x;            // 0..191; waves 0,1 = node cols, wave 2 = edge cols
    const int g0 = blockIdx.x * GPB;

    const float4* ge4  = reinterpret_cast<const float4*>(ge + (size_t)g0 * H);
    float4*       sge4 = reinterpret_cast<float4*>(sge);
    for (int i = t; i < GPB * H / 4; i += 192) sge4[i] = ge4[i];
    __syncthreads();

    const float4* w4;
    float bias;
    if (t < FN) { w4 = reinterpret_cast<const float4*>(node_w + (size_t)t * H);      bias = node_b[t]; }
    else        { w4 = reinterpret_cast<const float4*>(edge_w + (size_t)(t-FN) * H); bias = edge_b[t-FN]; }

    float acc[GPB];
    #pragma unroll
    for (int g = 0; g < GPB; ++g) acc[g] = 0.f;

    #pragma unroll 4
    for (int k = 0; k < H / 4; ++k) {
        const float4 wv = w4[k];
        #pragma unroll
        for (int g = 0; g < GPB; ++g) {
            const float* s = sge + g * H + k * 4;   // same addr across lanes -> LDS broadcast
            acc[g] += wv.x * s[0] + wv.y * s[1] + wv.z * s[2] + wv.w * s[3];
        }
    }

    #pragma unroll
    for (int g = 0; g < GPB; ++g) {
        const float v = acc[g] + bias;
        if (t < FN) P[(size_t)(g0 + g) * FN + t]        = v;
        else        Q[(size_t)(g0 + g) * FE + (t - FN)] = v;
    }
}

// Fused scatter: first half of the grid streams x_hat, second half edge_hat.
// Stores are non-temporal (nt) so the write stream doesn't allocate in L2.
__global__ __launch_bounds__(256) void scatter_fused(
    const int* __restrict__ batch,     // [N]
    const int* __restrict__ src,       // edge_index row 0 (E)
    const f4* __restrict__ P4,         // [B*32]
    const f4* __restrict__ Q4,         // [B*16]
    f4* __restrict__ xout,             // [N*32]
    f4* __restrict__ eout,             // [E*16]
    int n4, int e4, int halfBlocks, int Bm1, int Nm1)
{
    const int stride = halfBlocks * 256;
    if (blockIdx.x < (unsigned)halfBlocks) {
        // node phase: x_hat[i,:] = P[batch[i],:]
        for (int i = blockIdx.x * 256 + threadIdx.x; i < n4; i += stride) {
            const int row = i >> 5;
            const int c   = i & 31;
            const int g   = batch[row] & Bm1;
            __builtin_nontemporal_store(P4[(g << 5) + c], xout + i);
        }
    } else {
        // edge phase: edge_hat[e,:] = Q[batch[src[e]],:]
        for (int i = (blockIdx.x - halfBlocks) * 256 + threadIdx.x; i < e4; i += stride) {
            const int e = i >> 4;
            const int c = i & 15;
            int s = src[e];
            s = min(max(s, 0), Nm1);
            const int g = batch[s] & Bm1;
            __builtin_nontemporal_store(Q4[(g << 4) + c], eout + i);
        }
    }
}

extern "C" void kernel_launch(void* const* d_in, const int* in_sizes, int n_in,
                              void* d_out, int out_size, void* d_ws, size_t ws_size,
                              hipStream_t stream) {
    const float* ge     = (const float*)d_in[0];
    const int*   batch  = (const int*)  d_in[1];
    const int*   eidx   = (const int*)  d_in[2];
    const float* node_w = (const float*)d_in[3];
    const float* node_b = (const float*)d_in[4];
    const float* edge_w = (const float*)d_in[5];
    const float* edge_b = (const float*)d_in[6];

    const int B = in_sizes[0] / H;   // 4096
    const int N = in_sizes[1];       // 500000
    const int E = in_sizes[2] / 2;   // 1000000

    float* P = (float*)d_ws;                 // [B, FN]
    float* Q = P + (size_t)B * FN;           // [B, FE]

    float* x_hat = (float*)d_out;            // [N, FN]
    float* e_hat = x_hat + (size_t)N * FN;   // [E, FE]

    proj_kernel<<<B / GPB, 192, 0, stream>>>(ge, node_w, node_b, edge_w, edge_b, P, Q);

    const int n4 = N * (FN / 4);             // 16,000,000
    const int e4 = E * (FE / 4);             // 16,000,000
    const int halfBlocks = 1024;             // 2048 total = exactly resident (8 blocks/CU)
    scatter_fused<<<2 * halfBlocks, 256, 0, stream>>>(
        batch, eidx, (const f4*)P, (const f4*)Q, (f4*)x_hat, (f4*)e_hat,
        n4, e4, halfBlocks, B - 1, N - 1);
}